// Round 7
// baseline (157.172 us; speedup 1.0000x reference)
//
#include <hip/hip_runtime.h>
#include <hip/hip_bf16.h>

// B=8, S=128, E=50, D=300, DE=50 — ALL I/O FLOAT32.
// out: node[307200] | edge[6553600].
//
// R6 change: k_node (34us, VALU-serial, 10 barriers) replaced by
//   k_prep      : msum->Mbf bf16 + transposed bf16 operand tables (xT, WwT,
//                 RW2T, rwPre) in ws. Barrier-free streaming.
//   k_node_mfma : 64 blocks x 256thr; 16-row tile; GEMM1 (M@x), GEMM2 (@Ww),
//                 GEMM3 (src@RW2) all on MFMA; LN in-register; 3 barriers.
// Fragment layouts copied verbatim from the proven k_edge MFMA path:
//   A: lane lr=row,  k = ks*32 + q*8 (8 contig bf16)
//   B: lane lr=col,  same k
//   C: col = lane&15, row = (lane>>4)*4 + r
//
// ws (floats): R1[51200] | R2[51200] | rwPre[2304] | Mbf[32768] |
//              xT[155648] | WwT[48640] | RW2T[19712]   (~1.6 MB total)

typedef __bf16 bf16x8 __attribute__((ext_vector_type(8)));
typedef float f32x4 __attribute__((ext_vector_type(4)));

__device__ __forceinline__ unsigned short f2bf(float f) {
    __hip_bfloat16 h = __float2bfloat16(f);
    union { __hip_bfloat16 h; unsigned short u; } c; c.h = h; return c.u;
}

// ---------------- K0: prep — msum + bf16 operand tables ----------------------
__global__ void __launch_bounds__(256) k_prep(
    const float* __restrict__ wps,
    const float* __restrict__ x,
    const float* __restrict__ Ww,
    const float* __restrict__ Rw,
    unsigned short* __restrict__ Mbf,     // [1024][128]
    unsigned short* __restrict__ xT,      // [8][304][128]
    unsigned short* __restrict__ WwT,     // [304][320]
    unsigned short* __restrict__ RW2T,    // [112][352]
    unsigned short* __restrict__ rwPre)   // [64][72]
{
    int tid = threadIdx.x, blk = blockIdx.x;
    int row0 = blk * 2;
    int i0 = row0 & 127;

    // ---- msum: 256 threads, one (r,j) pair each (2 rows x 128 j) ----
    {
        int r = tid >> 7, j = tid & 127;
        const float2* p2 = (const float2*)(wps + ((size_t)(row0 + r) * 128 + j) * 50);
        float s = 0.f;
#pragma unroll
        for (int n = 0; n < 25; ++n) { float2 v = p2[n]; s += v.x + v.y; }
        float m = s * (1.0f / 50.0f) + (((i0 + r) == j) ? 1.0f : 0.0f);
        Mbf[(size_t)(row0 + r) * 128 + j] = f2bf(m);
    }

    // ---- side jobs (block-partitioned, no barriers) ----
    if (blk < 64) {                       // xT slice: batch bb, 16 j-rows
        int bb = blk >> 3, j0 = (blk & 7) * 16;
        const float* xb = x + (size_t)bb * 38400;
        for (int el = tid; el < 4800; el += 256) {
            int j = j0 + el / 300, d = el % 300;
            xT[((size_t)bb * 304 + d) * 128 + j] = f2bf(xb[j * 300 + d]);
        }
        if (tid < 64) {                   // zero pad rows d=300..303
            int d = 300 + (tid >> 4), j = j0 + (tid & 15);
            xT[((size_t)bb * 304 + d) * 128 + j] = 0;
        }
    } else if (blk < 140) {               // WwT: 4 d-rows per block
        int d0 = (blk - 64) * 4;
        for (int el = tid; el < 1280; el += 256) {
            int d = d0 + el / 320, k = el % 320;
            unsigned short v = 0;
            if (d < 300 && k < 300) v = f2bf(Ww[k * 300 + d]);
            WwT[d * 320 + k] = v;
        }
    } else if (blk < 168) {               // RW2T: 4 q-rows per block
        int r0 = (blk - 140) * 4;
        for (int el = tid; el < 1408; el += 256) {
            int row = r0 + el / 352, idx = el % 352;
            unsigned short v = 0;
            if (row < 50) {
                if (idx < 50)       v = f2bf(Rw[(50 + idx) * 50 + row]);
                else if (idx < 350) v = f2bf(Rw[(150 + idx - 50) * 50 + row]);
            } else if (row < 100) {
                int q = row - 50;
                if (idx < 50)       v = f2bf(Rw[(100 + idx) * 50 + q]);
                else if (idx < 350) v = f2bf(Rw[(450 + idx - 50) * 50 + q]);
            }
            RW2T[row * 352 + idx] = v;
        }
    } else if (blk == 200) {              // rwPre for k_edge (B = Rw[0:50]^T)
        for (int idx = tid; idx < 4608; idx += 256) {
            int kk = idx / 72, e = idx % 72;
            rwPre[idx] = (kk < 50 && e < 50) ? f2bf(Rw[e * 50 + kk]) : (unsigned short)0;
        }
    }
}

// ---------------- K1: node pipeline on MFMA — 64 blocks x 256 thr -------------
__global__ void __launch_bounds__(256) k_node_mfma(
    const unsigned short* __restrict__ Mbf,
    const unsigned short* __restrict__ xT,
    const unsigned short* __restrict__ WwT,
    const unsigned short* __restrict__ RW2T,
    const float* __restrict__ wa,
    const float* __restrict__ Wb,
    const float* __restrict__ lna,
    const float* __restrict__ lnb,
    const float* __restrict__ rb,
    float* __restrict__ node_out,
    float* __restrict__ R1, float* __restrict__ R2)
{
    __shared__ __align__(16) unsigned short a2bf[16 * 344];  // Axm bf16 [16][344]
    __shared__ __align__(16) float hL[16 * 308];             // h f32 [16][308]
    __shared__ __align__(16) unsigned short srcbf[16 * 360]; // [diag|node] bf16

    int tid = threadIdx.x;
    int b = blockIdx.x >> 3, i0 = (blockIdx.x & 7) * 16;
    int brow = b * 128 + i0;
    int lane = tid & 63, wv = tid >> 6;
    int q = lane >> 4, lr = lane & 15;

    // ---- stage0: zero LDS pads + diag(wa) -> srcbf[:,0:50) ----
    for (int i = tid; i < 640; i += 256) { int m = i / 40; a2bf[m * 344 + 304 + i % 40] = 0; }
    if (tid < 160) { int m = tid / 10; srcbf[m * 360 + 350 + tid % 10] = 0; }
    for (int i = tid; i < 800; i += 256) {
        int m = i / 50, e = i % 50;
        srcbf[m * 360 + e] = f2bf(wa[((size_t)(brow + m) * 128 + (i0 + m)) * 50 + e]);
    }

    // ---- GEMM1: Axm[16,300] = M[16,128] @ xT^T  (B = xT[n=d][k=j]) ----
    bf16x8 A1[4];
#pragma unroll
    for (int ks = 0; ks < 4; ++ks)
        A1[ks] = *(const bf16x8*)&Mbf[(size_t)(brow + lr) * 128 + ks * 32 + q * 8];
    for (int nt = wv; nt < 19; nt += 4) {
        f32x4 acc = {0.f, 0.f, 0.f, 0.f};
#pragma unroll
        for (int ks = 0; ks < 4; ++ks) {
            bf16x8 bb = *(const bf16x8*)&xT[((size_t)b * 304 + nt * 16 + lr) * 128 + ks * 32 + q * 8];
            acc = __builtin_amdgcn_mfma_f32_16x16x32_bf16(A1[ks], bb, acc, 0, 0, 0);
        }
#pragma unroll
        for (int r = 0; r < 4; ++r)
            a2bf[(q * 4 + r) * 344 + nt * 16 + lr] = f2bf(acc[r]);
    }
    __syncthreads();

    // ---- GEMM2: h[16,300] = Axm @ Ww  (A from LDS, B = WwT[n=d][k]) ----
    bf16x8 A2[10];
#pragma unroll
    for (int ks = 0; ks < 10; ++ks)
        A2[ks] = *(const bf16x8*)&a2bf[lr * 344 + ks * 32 + q * 8];
    for (int nt = wv; nt < 19; nt += 4) {
        f32x4 acc = {0.f, 0.f, 0.f, 0.f};
#pragma unroll
        for (int ks = 0; ks < 10; ++ks) {
            bf16x8 bb = *(const bf16x8*)&WwT[(size_t)(nt * 16 + lr) * 320 + ks * 32 + q * 8];
            acc = __builtin_amdgcn_mfma_f32_16x16x32_bf16(A2[ks], bb, acc, 0, 0, 0);
        }
        int n = nt * 16 + lr;
        float wbv = (n < 300) ? Wb[n] : 0.f;
#pragma unroll
        for (int r = 0; r < 4; ++r)
            hL[(q * 4 + r) * 308 + n] = (n < 300) ? (acc[r] + wbv) : 0.f;
    }
    __syncthreads();

    // ---- LN (in-register stats per 16-lane group) + relu -> node_out, srcbf --
    {
        int trow = tid >> 4, c = tid & 15;
        float s1 = 0.f, s2 = 0.f;
#pragma unroll
        for (int kk = 0; kk < 19; ++kk) {
            float v = hL[trow * 308 + c + kk * 16];   // pads are 0
            s1 += v; s2 += v * v;
        }
#pragma unroll
        for (int off = 1; off < 16; off <<= 1) {
            s1 += __shfl_xor(s1, off);
            s2 += __shfl_xor(s2, off);
        }
        float mean = s1 * (1.0f / 300.0f);
        float var = (s2 - 300.0f * mean * mean) * (1.0f / 299.0f);
        var = fmaxf(var, 0.0f);
        float rstd = 1.0f / (sqrtf(var) + 1e-6f);
        float* nrow = node_out + (size_t)(brow + trow) * 300;
#pragma unroll
        for (int kk = 0; kk < 19; ++kk) {
            int n = c + kk * 16;
            if (n < 300) {
                float v = lna[n] * (hL[trow * 308 + n] - mean) * rstd + lnb[n];
                v = fmaxf(v, 0.f);
                nrow[n] = v;
                srcbf[trow * 360 + 50 + n] = f2bf(v);
            }
        }
    }
    __syncthreads();

    // ---- GEMM3: [R1|R2][16,100] = src[16,350] @ RW2T^T ----
    bf16x8 A3[11];
#pragma unroll
    for (int ks = 0; ks < 11; ++ks)
        A3[ks] = *(const bf16x8*)&srcbf[lr * 360 + ks * 32 + q * 8];
    for (int nt = wv; nt < 7; nt += 4) {
        f32x4 acc = {0.f, 0.f, 0.f, 0.f};
#pragma unroll
        for (int ks = 0; ks < 11; ++ks) {
            bf16x8 bb = *(const bf16x8*)&RW2T[(size_t)(nt * 16 + lr) * 352 + ks * 32 + q * 8];
            acc = __builtin_amdgcn_mfma_f32_16x16x32_bf16(A3[ks], bb, acc, 0, 0, 0);
        }
        int qq = nt * 16 + lr;
#pragma unroll
        for (int r = 0; r < 4; ++r) {
            int m = q * 4 + r;
            if (qq < 50)       R1[(size_t)(brow + m) * 50 + qq] = acc[r];
            else if (qq < 100) R2[(size_t)(brow + m) * 50 + qq - 50] = acc[r] + rb[qq - 50];
        }
    }
}

// ---------------- K2: edge_out = wa·Rw[0:50] (MFMA) + R1[j] + R2[i] ------------
typedef float f32x4_u __attribute__((ext_vector_type(4))) __attribute__((aligned(4)));

__device__ __forceinline__ bf16x8 fragA(const float* __restrict__ ap, int e0) {
    union { bf16x8 v; unsigned short u[8]; } c;
    if (e0 <= 40) {
        f32x4_u v0 = *(const f32x4_u*)(ap + e0);
        f32x4_u v1 = *(const f32x4_u*)(ap + e0 + 4);
#pragma unroll
        for (int i = 0; i < 4; ++i) { c.u[i] = f2bf(v0[i]); c.u[4 + i] = f2bf(v1[i]); }
    } else if (e0 == 48) {
        c.u[0] = f2bf(ap[48]); c.u[1] = f2bf(ap[49]);
#pragma unroll
        for (int i = 2; i < 8; ++i) c.u[i] = 0;
    } else {
#pragma unroll
        for (int i = 0; i < 8; ++i) c.u[i] = 0;
    }
    return c.v;
}

__global__ void __launch_bounds__(256) k_edge(
    const float* __restrict__ wa,
    const unsigned int* __restrict__ rwPre,
    const float* __restrict__ R1, const float* __restrict__ R2,
    float* __restrict__ eout)
{
    __shared__ __align__(16) unsigned char smem[25600];
    unsigned short* rwBT = (unsigned short*)smem;   // 64*72 bf16 (pre-formatted)
    float* outF = (float*)smem;                     // alias after MFMA barrier
    int tid = threadIdx.x;
    int bi = blockIdx.x;       // b*128 + i
    int b = bi >> 7;

    for (int idx = tid; idx < 2304; idx += 256)
        ((unsigned int*)rwBT)[idx] = rwPre[idx];
    __syncthreads();

    int lane = tid & 63, wv = tid >> 6;
    int q = lane >> 4, lr = lane & 15;
    const float* wab = wa + (size_t)bi * 6400;
    f32x4 acc[2][4] = {};

#pragma unroll
    for (int mi = 0; mi < 2; ++mi) {
        const float* ap = wab + (wv * 32 + mi * 16 + lr) * 50;
#pragma unroll
        for (int ks = 0; ks < 2; ++ks) {
            int e0 = ks * 32 + q * 8;
            bf16x8 a = fragA(ap, e0);
#pragma unroll
            for (int nt = 0; nt < 4; ++nt) {
                bf16x8 bb = *(const bf16x8*)&rwBT[(nt * 16 + lr) * 72 + e0];
                acc[mi][nt] = __builtin_amdgcn_mfma_f32_16x16x32_bf16(a, bb, acc[mi][nt], 0, 0, 0);
            }
        }
    }
    __syncthreads();   // rwBT dead; alias smem as outF

    const float* r2p = R2 + (size_t)bi * 50;
#pragma unroll
    for (int nt = 0; nt < 4; ++nt) {
        int kk = nt * 16 + lr;
        if (kk < 50) {
            float r2v = r2p[kk];
#pragma unroll
            for (int mi = 0; mi < 2; ++mi) {
                int jbase = wv * 32 + mi * 16 + q * 4;
#pragma unroll
                for (int r = 0; r < 4; ++r)
                    outF[(jbase + r) * 50 + kk] = acc[mi][nt][r] + r2v;
            }
        }
    }
    __syncthreads();

    const float4* R1b = (const float4*)(R1 + (size_t)b * 6400);
    const float4* L4  = (const float4*)outF;
    float4* op4 = (float4*)(eout + (size_t)bi * 6400);
    for (int f4 = tid; f4 < 1600; f4 += 256) {
        float4 v = L4[f4];
        float4 r = R1b[f4];
        v.x += r.x; v.y += r.y; v.z += r.z; v.w += r.w;
        op4[f4] = v;
    }
}

extern "C" void kernel_launch(void* const* d_in, const int* in_sizes, int n_in,
                              void* d_out, int out_size, void* d_ws, size_t ws_size,
                              hipStream_t stream)
{
    const float* wps = (const float*)d_in[0];
    const float* wa  = (const float*)d_in[1];
    const float* x   = (const float*)d_in[2];
    // d_in[3] self_loop: identity on every channel, folded into msum (+1 on diag)
    const float* Ww  = (const float*)d_in[4];
    const float* Wb  = (const float*)d_in[5];
    const float* lna = (const float*)d_in[6];
    const float* lnb = (const float*)d_in[7];
    const float* Rw  = (const float*)d_in[8];
    const float* rb  = (const float*)d_in[9];

    float* wsf = (float*)d_ws;
    float* R1 = wsf;                                          // 51200 f
    float* R2 = wsf + 51200;                                  // 51200 f
    unsigned short* rwPre16 = (unsigned short*)(wsf + 102400); // 4608 u16 (2304 f)
    unsigned short* Mbf  = (unsigned short*)(wsf + 104704);    // 131072 u16
    unsigned short* xT   = (unsigned short*)(wsf + 170240);    // 311296 u16
    unsigned short* WwT  = (unsigned short*)(wsf + 325888);    // 97280 u16
    unsigned short* RW2T = (unsigned short*)(wsf + 374528);    // 39424 u16

    float* node_out = (float*)d_out;             // 307200 floats
    float* edge_out = node_out + 307200;         // 6553600 floats

    k_prep<<<512, 256, 0, stream>>>(wps, x, Ww, Rw, Mbf, xT, WwT, RW2T, rwPre16);
    k_node_mfma<<<64, 256, 0, stream>>>(Mbf, xT, WwT, RW2T, wa, Wb, lna, lnb, rb,
                                        node_out, R1, R2);
    k_edge<<<1024, 256, 0, stream>>>(wa, (const unsigned int*)rwPre16, R1, R2, edge_out);
}